// Round 6
// baseline (351.852 us; speedup 1.0000x reference)
//
#include <hip/hip_runtime.h>

#define NN 8000
#define FD 256
#define NEG_SLOPE 0.2f
#define NCH 5                 // j chunks
#define JQ (NN / NCH)         // 1600
#define NSJ (JQ / 32)         // 50 j-steps per wave
#define NRG (NN / 32)         // 250 row groups

typedef __bf16 bf16;
typedef __bf16 bf16x8 __attribute__((ext_vector_type(8)));
typedef float f32x4 __attribute__((ext_vector_type(4)));

// ---------------- K1: H = X @ W^T + b -> Ht (bf16, transposed [f][i]) ----------------
__global__ __launch_bounds__(256) void k_linear(const float* __restrict__ X,
                                                const float* __restrict__ W,
                                                const float* __restrict__ b,
                                                bf16* __restrict__ Ht) {
    __shared__ float Xs[16][260];
    const int t = threadIdx.x;
    const int i0 = blockIdx.x * 16;
    #pragma unroll
    for (int r = 0; r < 16; ++r)
        Xs[r][t] = X[(size_t)(i0 + r) * FD + t];
    __syncthreads();
    const int f = t;
    float acc[16];
    const float bf_ = b[f];
    #pragma unroll
    for (int ii = 0; ii < 16; ++ii) acc[ii] = bf_;
    for (int k4 = 0; k4 < FD / 4; ++k4) {
        const float4 w4 = *(const float4*)&W[(size_t)f * FD + k4 * 4];
        #pragma unroll
        for (int ii = 0; ii < 16; ++ii) {
            const float4 x4 = *(const float4*)&Xs[ii][k4 * 4];
            acc[ii] += x4.x * w4.x + x4.y * w4.y + x4.z * w4.z + x4.w * w4.w;
        }
    }
    bf16x8 v0, v1;
    #pragma unroll
    for (int ii = 0; ii < 8; ++ii) { v0[ii] = (bf16)acc[ii]; v1[ii] = (bf16)acc[ii + 8]; }
    *(bf16x8*)&Ht[(size_t)f * NN + i0]     = v0;
    *(bf16x8*)&Ht[(size_t)f * NN + i0 + 8] = v1;
}

// ---------------- K2: hs = H@a_src + a_b, hd = H@a_dst ----------------
__global__ __launch_bounds__(256) void k_attn_vec(const bf16* __restrict__ Ht,
                                                  const float* __restrict__ a_src,
                                                  const float* __restrict__ a_dst,
                                                  const float* __restrict__ a_b,
                                                  float* __restrict__ hs,
                                                  float* __restrict__ hd) {
    __shared__ float psh[4][64], pdh[4][64];
    const int t = threadIdx.x;
    const int li = t & 63;
    const int q = t >> 6;
    const int i = blockIdx.x * 64 + li;
    float ps = 0.f, pd = 0.f;
    #pragma unroll 8
    for (int fi = 0; fi < 64; ++fi) {
        const int f = q * 64 + fi;
        const float h = (float)Ht[(size_t)f * NN + i];
        ps += h * a_src[f];
        pd += h * a_dst[f];
    }
    psh[q][li] = ps; pdh[q][li] = pd;
    __syncthreads();
    if (q == 0) {
        ps = psh[0][li] + psh[1][li] + psh[2][li] + psh[3][li];
        pd = pdh[0][li] + pdh[1][li] + pdh[2][li] + pdh[3][li];
        hs[i] = ps + a_b[0];
        hd[i] = pd;
    }
}

__device__ __forceinline__ bf16x8 wcompute(int4 alo, int4 ahi, float4 hlo, float4 hhi,
                                           float hsv, float& ls) {
    float w[8]; float e;
    e = hsv + hlo.x; e = e >= 0.f ? e : NEG_SLOPE * e; w[0] = alo.x ? __expf(e) : 0.f;
    e = hsv + hlo.y; e = e >= 0.f ? e : NEG_SLOPE * e; w[1] = alo.y ? __expf(e) : 0.f;
    e = hsv + hlo.z; e = e >= 0.f ? e : NEG_SLOPE * e; w[2] = alo.z ? __expf(e) : 0.f;
    e = hsv + hlo.w; e = e >= 0.f ? e : NEG_SLOPE * e; w[3] = alo.w ? __expf(e) : 0.f;
    e = hsv + hhi.x; e = e >= 0.f ? e : NEG_SLOPE * e; w[4] = ahi.x ? __expf(e) : 0.f;
    e = hsv + hhi.y; e = e >= 0.f ? e : NEG_SLOPE * e; w[5] = ahi.y ? __expf(e) : 0.f;
    e = hsv + hhi.z; e = e >= 0.f ? e : NEG_SLOPE * e; w[6] = ahi.z ? __expf(e) : 0.f;
    e = hsv + hhi.w; e = e >= 0.f ? e : NEG_SLOPE * e; w[7] = ahi.w ? __expf(e) : 0.f;
    ls += ((w[0] + w[1]) + (w[2] + w[3])) + ((w[4] + w[5]) + (w[6] + w[7]));
    bf16x8 r;
    #pragma unroll
    for (int i = 0; i < 8; ++i) r[i] = (bf16)w[i];
    return r;
}

// ---------------- K3: barrier-free fused GAT ----------------
// One wave per (32-row group, f-half of 128, j-chunk of 1600). The lane that
// computes w IS the MFMA A-lane (A layout: row=l&15, k=(l>>4)*8+e — HW-validated
// R2/R5). No LDS, no barriers, no cross-lane ops in the K-loop. B-frags
// global->reg from L2-resident Ht. adj/hd prefetched one step ahead in regs.
__global__ __launch_bounds__(256) void k_gat(const bf16* __restrict__ Ht,
                                             const int* __restrict__ adj,
                                             const float* __restrict__ hs,
                                             const float* __restrict__ hd,
                                             float* __restrict__ out,
                                             float* __restrict__ lg2) {
    const int t = threadIdx.x;
    const int l = t & 63;
    const int g = blockIdx.x * 4 + (t >> 6);   // global wave id, 0..2499
    const int rg = g % NRG;                    // row group (32 rows)
    const int fh = (g / NRG) & 1;              // f half
    const int ch = g / (2 * NRG);              // j chunk
    const int i0 = rg * 32;
    const int jq0 = ch * JQ;
    const int f0 = fh * 128;
    const int al = l & 15, asl = l >> 4;

    const int*   adjpA = adj + (size_t)(i0 + al) * NN + jq0 + asl * 8;
    const int*   adjpB = adjpA + (size_t)16 * NN;
    const float* hdp   = hd + jq0 + asl * 8;
    const bf16*  bp    = Ht + (size_t)(f0 + al) * NN + jq0 + asl * 8;

    const float hsA = hs[i0 + al];
    const float hsB = hs[i0 + 16 + al];

    f32x4 acc0[8], acc1[8];
    #pragma unroll
    for (int fg = 0; fg < 8; ++fg) {
        acc0[fg] = (f32x4){0.f, 0.f, 0.f, 0.f};
        acc1[fg] = (f32x4){0.f, 0.f, 0.f, 0.f};
    }
    float rs0 = 0.f, rs1 = 0.f;

    int4   aA0 = *(const int4*)adjpA;
    int4   aA1 = *(const int4*)(adjpA + 4);
    int4   aB0 = *(const int4*)adjpB;
    int4   aB1 = *(const int4*)(adjpB + 4);
    float4 h0  = *(const float4*)hdp;
    float4 h1  = *(const float4*)(hdp + 4);

    #pragma unroll 1
    for (int s = 0; s < NSJ; ++s) {
        // prefetch next step's adj/hd (HBM/L3 long pole)
        int4 nA0, nA1, nB0, nB1; float4 nh0, nh1;
        if (s + 1 < NSJ) {
            const int o = (s + 1) * 32;
            nA0 = *(const int4*)(adjpA + o);
            nA1 = *(const int4*)(adjpA + o + 4);
            nB0 = *(const int4*)(adjpB + o);
            nB1 = *(const int4*)(adjpB + o + 4);
            nh0 = *(const float4*)(hdp + o);
            nh1 = *(const float4*)(hdp + o + 4);
        }
        // issue all B-frag loads (L2)
        bf16x8 b[8];
        #pragma unroll
        for (int fg = 0; fg < 8; ++fg)
            b[fg] = *(const bf16x8*)(bp + (size_t)fg * 16 * NN + s * 32);

        // compute own A-fragments (16 exps)
        const bf16x8 a0v = wcompute(aA0, aA1, h0, h1, hsA, rs0);
        const bf16x8 a1v = wcompute(aB0, aB1, h0, h1, hsB, rs1);

        // 16 MFMAs
        #pragma unroll
        for (int fg = 0; fg < 8; ++fg) {
            acc0[fg] = __builtin_amdgcn_mfma_f32_16x16x32_bf16(a0v, b[fg], acc0[fg], 0, 0, 0);
            acc1[fg] = __builtin_amdgcn_mfma_f32_16x16x32_bf16(a1v, b[fg], acc1[fg], 0, 0, 0);
        }

        aA0 = nA0; aA1 = nA1; aB0 = nB0; aB1 = nB1; h0 = nh0; h1 = nh1;
    }

    // row sums: lanes {l, l^16, l^32, l^48} share a row
    rs0 += __shfl_xor(rs0, 16); rs0 += __shfl_xor(rs0, 32);
    rs1 += __shfl_xor(rs1, 16); rs1 += __shfl_xor(rs1, 32);
    if (fh == 0 && l < 16) {
        lg2[(size_t)ch * NN + i0 + al]      = rs0;
        lg2[(size_t)ch * NN + i0 + 16 + al] = rs1;
    }

    // numerator: NCH atomic contributions per element
    #pragma unroll
    for (int fg = 0; fg < 8; ++fg) {
        #pragma unroll
        for (int gi = 0; gi < 4; ++gi) {
            atomicAdd(&out[(size_t)(i0 + asl * 4 + gi) * FD + f0 + fg * 16 + al],      acc0[fg][gi]);
            atomicAdd(&out[(size_t)(i0 + 16 + asl * 4 + gi) * FD + f0 + fg * 16 + al], acc1[fg][gi]);
        }
    }
}

// ---------------- K4: normalize by row sums ----------------
__global__ __launch_bounds__(256) void k_norm(float* __restrict__ out,
                                              const float* __restrict__ lg2) {
    const int i = blockIdx.x;
    float s = 0.f;
    #pragma unroll
    for (int c = 0; c < NCH; ++c) s += lg2[(size_t)c * NN + i];
    const float rinv = 1.0f / s;
    out[(size_t)i * FD + threadIdx.x] *= rinv;
}

extern "C" void kernel_launch(void* const* d_in, const int* in_sizes, int n_in,
                              void* d_out, int out_size, void* d_ws, size_t ws_size,
                              hipStream_t stream) {
    const float* X     = (const float*)d_in[0];
    const int*   adj   = (const int*)d_in[1];
    const float* Ww    = (const float*)d_in[2];
    const float* Wb    = (const float*)d_in[3];
    const float* a_src = (const float*)d_in[4];
    const float* a_dst = (const float*)d_in[5];
    const float* a_b   = (const float*)d_in[6];
    float* out = (float*)d_out;

    bf16*  Ht  = (bf16*)d_ws;                                 // 4.096 MB
    float* hs  = (float*)((char*)d_ws + (size_t)FD * NN * sizeof(bf16));
    float* hd  = hs + NN;
    float* lg2 = hd + NN;                                     // NCH * NN floats

    hipMemsetAsync(out, 0, (size_t)NN * FD * sizeof(float), stream);

    k_linear<<<NN / 16, 256, 0, stream>>>(X, Ww, Wb, Ht);
    k_attn_vec<<<NN / 64, 256, 0, stream>>>(Ht, a_src, a_dst, a_b, hs, hd);
    k_gat<<<(NRG * 2 * NCH) / 4, 256, 0, stream>>>(Ht, adj, hs, hd, out, lg2);
    k_norm<<<NN, 256, 0, stream>>>(out, lg2);
}

// Round 7
// 151.806 us; speedup vs baseline: 2.3178x; 2.3178x over previous
//
#include <hip/hip_runtime.h>

#define NN 8000
#define FD 256
#define NEG_SLOPE 0.2f
#define BM 32
#define KT 64

typedef __bf16 bf16;
typedef __bf16 bf16x8 __attribute__((ext_vector_type(8)));
typedef __bf16 bf16x4 __attribute__((ext_vector_type(4)));
typedef float f32x4 __attribute__((ext_vector_type(4)));

// ---------------- K1: H = X @ W^T + b -> Ht (bf16, transposed [f][i]) ----------------
__global__ __launch_bounds__(256) void k_linear(const float* __restrict__ X,
                                                const float* __restrict__ W,
                                                const float* __restrict__ b,
                                                bf16* __restrict__ Ht) {
    __shared__ float Xs[16][260];
    const int t = threadIdx.x;
    const int i0 = blockIdx.x * 16;
    #pragma unroll
    for (int r = 0; r < 16; ++r)
        Xs[r][t] = X[(size_t)(i0 + r) * FD + t];
    __syncthreads();
    const int f = t;
    float acc[16];
    const float bf_ = b[f];
    #pragma unroll
    for (int ii = 0; ii < 16; ++ii) acc[ii] = bf_;
    for (int k4 = 0; k4 < FD / 4; ++k4) {
        const float4 w4 = *(const float4*)&W[(size_t)f * FD + k4 * 4];
        #pragma unroll
        for (int ii = 0; ii < 16; ++ii) {
            const float4 x4 = *(const float4*)&Xs[ii][k4 * 4];
            acc[ii] += x4.x * w4.x + x4.y * w4.y + x4.z * w4.z + x4.w * w4.w;
        }
    }
    bf16x8 v0, v1;
    #pragma unroll
    for (int ii = 0; ii < 8; ++ii) { v0[ii] = (bf16)acc[ii]; v1[ii] = (bf16)acc[ii + 8]; }
    *(bf16x8*)&Ht[(size_t)f * NN + i0]     = v0;
    *(bf16x8*)&Ht[(size_t)f * NN + i0 + 8] = v1;
}

// ---------------- K2: hs = H@a_src + a_b, hd = H@a_dst ----------------
__global__ __launch_bounds__(256) void k_attn_vec(const bf16* __restrict__ Ht,
                                                  const float* __restrict__ a_src,
                                                  const float* __restrict__ a_dst,
                                                  const float* __restrict__ a_b,
                                                  float* __restrict__ hs,
                                                  float* __restrict__ hd) {
    __shared__ float psh[4][64], pdh[4][64];
    const int t = threadIdx.x;
    const int li = t & 63;
    const int q = t >> 6;
    const int i = blockIdx.x * 64 + li;
    float ps = 0.f, pd = 0.f;
    #pragma unroll 8
    for (int fi = 0; fi < 64; ++fi) {
        const int f = q * 64 + fi;
        const float h = (float)Ht[(size_t)f * NN + i];
        ps += h * a_src[f];
        pd += h * a_dst[f];
    }
    psh[q][li] = ps; pdh[q][li] = pd;
    __syncthreads();
    if (q == 0) {
        ps = psh[0][li] + psh[1][li] + psh[2][li] + psh[3][li];
        pd = pdh[0][li] + pdh[1][li] + pdh[2][li] + pdh[3][li];
        hs[i] = ps + a_b[0];
        hd[i] = pd;
    }
}

// ---------------- K3: R2 engine, occupancy-repaired ----------------
// 512 thr (8 waves, 1 row-strip x 8 col-groups), BM=32, KT=64, j-split x2
// (grid 500 -> all blocks resident, 2 blocks/CU). B-tile staged via
// global_load_lds (source slot-XOR, linear LDS dest, read slot-XOR); Wt
// slot-XOR within row. Counted vmcnt(6); 2 raw barriers/step. No hd_s.
__global__ __launch_bounds__(512, 4) void k_gat(const bf16* __restrict__ Ht,
                                                const int* __restrict__ adj,
                                                const float* __restrict__ hs,
                                                const float* __restrict__ hd,
                                                float* __restrict__ out,
                                                float* __restrict__ lg) {
    __shared__ __attribute__((aligned(16))) bf16 Bt[2][FD * KT];  // 2 x 32 KB
    __shared__ __attribute__((aligned(16))) bf16 Wt[2][BM * KT];  // 2 x 4 KB

    const int t  = threadIdx.x;
    const int l  = t & 63;
    const int wv = t >> 6;
    const int ib = blockIdx.x >> 1;
    const int jb = blockIdx.x & 1;
    const int i0 = ib * BM;
    const int jq0 = jb * 4032;          // jb=0: 63 steps, jb=1: 62 steps
    const int NS = 63 - jb;

    // weight mapping: thread owns row r, 4 j's at jm
    const int r  = t >> 4;
    const int jm = (t & 15) * 4;
    const float hsv = hs[i0 + r];
    const int woff = r * KT + (((jm >> 3) ^ (r & 7)) << 3) + (((jm >> 2) & 1) << 2);
    const int* adjp  = adj + (size_t)(i0 + r) * NN + jq0 + jm;
    const float* hdp = hd + jq0 + jm;

    // MFMA mapping
    const int al = l & 15, asl = l >> 4;
    const int cswz = al & 7;
    const int colb = wv * 32 + al;

    // stage: linear LDS dest (wave-uniform base + lane*16), source slot-XOR
    auto stage = [&](int s_, int bufi) {
        #pragma unroll
        for (int q = 0; q < 4; ++q) {
            const int idx = q * 512 + t;
            const int col = idx >> 3;
            const int sslot = (idx & 7) ^ (col & 7);
            const bf16* src = Ht + (size_t)col * NN + jq0 + s_ * KT + sslot * 8;
            bf16* dst = &Bt[bufi][(size_t)(q * 512 + wv * 64) * 8];
            __builtin_amdgcn_global_load_lds(
                (const __attribute__((address_space(1))) void*)src,
                (__attribute__((address_space(3))) void*)dst, 16, 0, 0);
        }
    };

    stage(0, 0);
    int4   adjc = *(const int4*)adjp;
    float4 hdc  = *(const float4*)hdp;

    f32x4 acc00 = {0.f, 0.f, 0.f, 0.f}, acc01 = acc00, acc10 = acc00, acc11 = acc00;
    f32x4 acc20 = acc00, acc21 = acc00, acc30 = acc00, acc31 = acc00;
    float lsum = 0.f;

    #pragma unroll 1
    for (int s = 0; s < NS; ++s) {
        const int cur = s & 1;
        int4 adjn; float4 hdn;
        if (s + 1 < NS) {
            stage(s + 1, cur ^ 1);
            adjn = *(const int4*)(adjp + (size_t)(s + 1) * KT);
            hdn  = *(const float4*)(hdp + (size_t)(s + 1) * KT);
            asm volatile("s_waitcnt vmcnt(6)" ::: "memory");  // drain stage(s)+adjc+hdc
        } else {
            asm volatile("s_waitcnt vmcnt(0)" ::: "memory");
        }

        // weight phase: 4 w's
        {
            float e, w0, w1, w2, w3;
            e = hsv + hdc.x; e = e >= 0.f ? e : NEG_SLOPE * e; w0 = adjc.x ? __expf(e) : 0.f;
            e = hsv + hdc.y; e = e >= 0.f ? e : NEG_SLOPE * e; w1 = adjc.y ? __expf(e) : 0.f;
            e = hsv + hdc.z; e = e >= 0.f ? e : NEG_SLOPE * e; w2 = adjc.z ? __expf(e) : 0.f;
            e = hsv + hdc.w; e = e >= 0.f ? e : NEG_SLOPE * e; w3 = adjc.w ? __expf(e) : 0.f;
            lsum += (w0 + w1) + (w2 + w3);
            bf16x4 wp; wp[0] = (bf16)w0; wp[1] = (bf16)w1; wp[2] = (bf16)w2; wp[3] = (bf16)w3;
            *(bf16x4*)&Wt[cur][woff] = wp;
        }
        asm volatile("s_waitcnt lgkmcnt(0)" ::: "memory");
        __builtin_amdgcn_s_barrier();

        // MFMA phase: 4 A-frags (rows 0..31 x k 0..63), 4 B-frags per 2 cols
        {
            const bf16* wb = Wt[cur];
            const bf16* bb = Bt[cur];
            const bf16x8 a00 = *(const bf16x8*)&wb[(al)      * KT + (((0 + asl) ^ cswz) << 3)];
            const bf16x8 a01 = *(const bf16x8*)&wb[(al)      * KT + (((4 + asl) ^ cswz) << 3)];
            const bf16x8 a10 = *(const bf16x8*)&wb[(al + 16) * KT + (((0 + asl) ^ cswz) << 3)];
            const bf16x8 a11 = *(const bf16x8*)&wb[(al + 16) * KT + (((4 + asl) ^ cswz) << 3)];
            const bf16x8 b00 = *(const bf16x8*)&bb[(colb)      * KT + (((0 + asl) ^ cswz) << 3)];
            const bf16x8 b01 = *(const bf16x8*)&bb[(colb)      * KT + (((4 + asl) ^ cswz) << 3)];
            const bf16x8 b10 = *(const bf16x8*)&bb[(colb + 16) * KT + (((0 + asl) ^ cswz) << 3)];
            const bf16x8 b11 = *(const bf16x8*)&bb[(colb + 16) * KT + (((4 + asl) ^ cswz) << 3)];
            acc00 = __builtin_amdgcn_mfma_f32_16x16x32_bf16(a00, b00, acc00, 0, 0, 0);
            acc00 = __builtin_amdgcn_mfma_f32_16x16x32_bf16(a01, b01, acc00, 0, 0, 0);
            acc01 = __builtin_amdgcn_mfma_f32_16x16x32_bf16(a00, b10, acc01, 0, 0, 0);
            acc01 = __builtin_amdgcn_mfma_f32_16x16x32_bf16(a01, b11, acc01, 0, 0, 0);
            acc10 = __builtin_amdgcn_mfma_f32_16x16x32_bf16(a10, b00, acc10, 0, 0, 0);
            acc10 = __builtin_amdgcn_mfma_f32_16x16x32_bf16(a11, b01, acc10, 0, 0, 0);
            acc11 = __builtin_amdgcn_mfma_f32_16x16x32_bf16(a10, b10, acc11, 0, 0, 0);
            acc11 = __builtin_amdgcn_mfma_f32_16x16x32_bf16(a11, b11, acc11, 0, 0, 0);
        }
        asm volatile("s_waitcnt lgkmcnt(0)" ::: "memory");
        __builtin_amdgcn_s_barrier();

        adjc = adjn; hdc = hdn;
    }

    // row sums: 16 threads per row (consecutive lanes), then one atomic/row
    lsum += __shfl_xor(lsum, 1);
    lsum += __shfl_xor(lsum, 2);
    lsum += __shfl_xor(lsum, 4);
    lsum += __shfl_xor(lsum, 8);
    if ((t & 15) == 0) atomicAdd(&lg[i0 + r], lsum);

    // numerator: 2 atomic contributions per element (jb=0,1)
    #pragma unroll
    for (int g = 0; g < 4; ++g) {
        const int rr = asl * 4 + g;
        atomicAdd(&out[(size_t)(i0 + rr) * FD + wv * 32 + al],           acc00[g]);
        atomicAdd(&out[(size_t)(i0 + rr) * FD + wv * 32 + 16 + al],      acc01[g]);
        atomicAdd(&out[(size_t)(i0 + 16 + rr) * FD + wv * 32 + al],      acc10[g]);
        atomicAdd(&out[(size_t)(i0 + 16 + rr) * FD + wv * 32 + 16 + al], acc11[g]);
    }
    (void)acc20; (void)acc21; (void)acc30; (void)acc31;
}

// ---------------- K4: normalize by row sums ----------------
__global__ __launch_bounds__(256) void k_norm(float* __restrict__ out,
                                              const float* __restrict__ lg) {
    const int i = blockIdx.x;
    const float rinv = 1.0f / lg[i];
    out[(size_t)i * FD + threadIdx.x] *= rinv;
}

extern "C" void kernel_launch(void* const* d_in, const int* in_sizes, int n_in,
                              void* d_out, int out_size, void* d_ws, size_t ws_size,
                              hipStream_t stream) {
    const float* X     = (const float*)d_in[0];
    const int*   adj   = (const int*)d_in[1];
    const float* Ww    = (const float*)d_in[2];
    const float* Wb    = (const float*)d_in[3];
    const float* a_src = (const float*)d_in[4];
    const float* a_dst = (const float*)d_in[5];
    const float* a_b   = (const float*)d_in[6];
    float* out = (float*)d_out;

    bf16*  Ht = (bf16*)d_ws;                                  // 4.096 MB
    float* hs = (float*)((char*)d_ws + (size_t)FD * NN * sizeof(bf16));
    float* hd = hs + NN;
    float* lg = hd + NN;

    hipMemsetAsync(out, 0, (size_t)NN * FD * sizeof(float), stream);
    hipMemsetAsync(lg, 0, NN * sizeof(float), stream);

    k_linear<<<NN / 16, 256, 0, stream>>>(X, Ww, Wb, Ht);
    k_attn_vec<<<NN / 64, 256, 0, stream>>>(Ht, a_src, a_dst, a_b, hs, hd);
    k_gat<<<(NN / BM) * 2, 512, 0, stream>>>(Ht, adj, hs, hd, out, lg);
    k_norm<<<NN, 256, 0, stream>>>(out, lg);
}

// Round 8
// 150.917 us; speedup vs baseline: 2.3314x; 1.0059x over previous
//
#include <hip/hip_runtime.h>

#define NN 8000
#define FD 256
#define NEG_SLOPE 0.2f
#define BM 64
#define KT 32
#define JS 4
#define CHUNK 2016            // 63 steps; last chunk 1952 = 61 steps

typedef __bf16 bf16;
typedef __bf16 bf16x8 __attribute__((ext_vector_type(8)));
typedef __bf16 bf16x4 __attribute__((ext_vector_type(4)));
typedef float f32x4 __attribute__((ext_vector_type(4)));

// ---------------- K1: H = X @ W^T + b -> Ht (bf16, [f][i]); also zeroes out/lg ----
__global__ __launch_bounds__(256) void k_linear(const float* __restrict__ X,
                                                const float* __restrict__ W,
                                                const float* __restrict__ b,
                                                bf16* __restrict__ Ht,
                                                float* __restrict__ out,
                                                float* __restrict__ lg) {
    __shared__ float Xs[16][260];
    const int t = threadIdx.x;
    const int i0 = blockIdx.x * 16;
    // zero out (8 MB) and lg across the grid (replaces slow fillBuffer dispatches)
    {
        const int gt = blockIdx.x * 256 + t;          // 128000 threads
        const float4 z4 = {0.f, 0.f, 0.f, 0.f};
        float4* o4 = (float4*)out;
        #pragma unroll
        for (int k = 0; k < 4; ++k) o4[gt + k * 128000] = z4;   // 512000 float4s
        if (gt < NN) lg[gt] = 0.f;
    }
    #pragma unroll
    for (int r = 0; r < 16; ++r)
        Xs[r][t] = X[(size_t)(i0 + r) * FD + t];
    __syncthreads();
    const int f = t;
    float acc[16];
    const float bf_ = b[f];
    #pragma unroll
    for (int ii = 0; ii < 16; ++ii) acc[ii] = bf_;
    for (int k4 = 0; k4 < FD / 4; ++k4) {
        const float4 w4 = *(const float4*)&W[(size_t)f * FD + k4 * 4];
        #pragma unroll
        for (int ii = 0; ii < 16; ++ii) {
            const float4 x4 = *(const float4*)&Xs[ii][k4 * 4];
            acc[ii] += x4.x * w4.x + x4.y * w4.y + x4.z * w4.z + x4.w * w4.w;
        }
    }
    bf16x8 v0, v1;
    #pragma unroll
    for (int ii = 0; ii < 8; ++ii) { v0[ii] = (bf16)acc[ii]; v1[ii] = (bf16)acc[ii + 8]; }
    *(bf16x8*)&Ht[(size_t)f * NN + i0]     = v0;
    *(bf16x8*)&Ht[(size_t)f * NN + i0 + 8] = v1;
}

// ---------------- K2: hs = H@a_src + a_b, hd = H@a_dst ----------------
__global__ __launch_bounds__(256) void k_attn_vec(const bf16* __restrict__ Ht,
                                                  const float* __restrict__ a_src,
                                                  const float* __restrict__ a_dst,
                                                  const float* __restrict__ a_b,
                                                  float* __restrict__ hs,
                                                  float* __restrict__ hd) {
    __shared__ float psh[4][64], pdh[4][64];
    const int t = threadIdx.x;
    const int li = t & 63;
    const int q = t >> 6;
    const int i = blockIdx.x * 64 + li;
    float ps = 0.f, pd = 0.f;
    #pragma unroll 8
    for (int fi = 0; fi < 64; ++fi) {
        const int f = q * 64 + fi;
        const float h = (float)Ht[(size_t)f * NN + i];
        ps += h * a_src[f];
        pd += h * a_dst[f];
    }
    psh[q][li] = ps; pdh[q][li] = pd;
    __syncthreads();
    if (q == 0) {
        ps = psh[0][li] + psh[1][li] + psh[2][li] + psh[3][li];
        pd = pdh[0][li] + pdh[1][li] + pdh[2][li] + pdh[3][li];
        hs[i] = ps + a_b[0];
        hd[i] = pd;
    }
}

// ---------------- K3: BM=64/KT=32 fused weights + MFMA PV ----------------
// 512 thr (8 waves); wave = 4 row-strips x 2 col-frags (32 cols) -> 8 MFMA/step,
// LDS reads 6 KB/wave/step. Swizzle: slot' = slot ^ ((col>>2)&3) (bits 4-5 only,
// same involution on stage-source, Wt-writer, and readers; <=2-way conflicts).
// adj/hd issued BEFORE stage so compiler's adjc-wait leaves DMA in flight;
// counted vmcnt(4) after weight phase overlaps exp with the DMA drain.
__global__ __launch_bounds__(512, 4) void k_gat(const bf16* __restrict__ Ht,
                                                const int* __restrict__ adj,
                                                const float* __restrict__ hs,
                                                const float* __restrict__ hd,
                                                float* __restrict__ out,
                                                float* __restrict__ lg) {
    __shared__ __attribute__((aligned(16))) bf16 Bt[2][FD * KT];  // 2 x 16 KB
    __shared__ __attribute__((aligned(16))) bf16 Wt[2][BM * KT];  // 2 x 4 KB

    const int t  = threadIdx.x;
    const int l  = t & 63;
    const int wv = t >> 6;
    const int ib = blockIdx.x >> 2;
    const int jb = blockIdx.x & 3;
    const int i0 = ib * BM;
    const int jq0 = jb * CHUNK;
    const int NS = (jb < 3) ? 63 : 61;

    // weight mapping: thread owns row r (0..63), 4 j's at jm
    const int r  = t >> 3;
    const int jm = (t & 7) << 2;
    const float hsv = hs[i0 + r];
    const int* adjp  = adj + (size_t)(i0 + r) * NN + jq0 + jm;
    const float* hdp = hd + jq0 + jm;
    // Wt write byte offset: row*64 + (slot ^ ((r>>2)&3))*16 + half*8
    const int woff = r * 64 + (((jm >> 3) ^ ((r >> 2) & 3)) << 4) + (((jm >> 2) & 1) << 3);

    // MFMA mapping
    const int al = l & 15, asl = l >> 4;
    const int eff = (asl ^ ((al >> 2) & 3)) << 4;   // swizzled 16B-slot byte offset

    // stage: linear LDS dest; source k pre-swizzled (k = slot ^ ((col>>2)&3))
    auto stage = [&](int s_, int bufi) {
        #pragma unroll
        for (int q = 0; q < 2; ++q) {
            const int idx = q * 512 + t;
            const int col = idx >> 2;
            const int kk = (idx & 3) ^ ((col >> 2) & 3);
            const bf16* src = Ht + (size_t)col * NN + jq0 + s_ * KT + kk * 8;
            bf16* dst = &Bt[bufi][(q * 512 + wv * 64) * 8];
            __builtin_amdgcn_global_load_lds(
                (const __attribute__((address_space(1))) void*)src,
                (__attribute__((address_space(3))) void*)dst, 16, 0, 0);
        }
    };

    // prologue: adj/hd FIRST, then stage(0)
    int4   adjc = *(const int4*)adjp;
    float4 hdc  = *(const float4*)hdp;
    stage(0, 0);

    f32x4 acc[4][2];
    #pragma unroll
    for (int sr = 0; sr < 4; ++sr) {
        acc[sr][0] = (f32x4){0.f, 0.f, 0.f, 0.f};
        acc[sr][1] = (f32x4){0.f, 0.f, 0.f, 0.f};
    }
    float lsum = 0.f;

    #pragma unroll 1
    for (int s = 0; s < NS; ++s) {
        const int cur = s & 1;
        int4 adjn; float4 hdn;
        if (s + 1 < NS) {
            adjn = *(const int4*)(adjp + (size_t)(s + 1) * KT);
            hdn  = *(const float4*)(hdp + (size_t)(s + 1) * KT);
            stage(s + 1, cur ^ 1);
        }

        // weight phase: 4 w's (compiler waits only adjc/hdc; stage DMA stays in flight)
        {
            float e, w0, w1, w2, w3;
            e = hsv + hdc.x; e = e >= 0.f ? e : NEG_SLOPE * e; w0 = adjc.x ? __expf(e) : 0.f;
            e = hsv + hdc.y; e = e >= 0.f ? e : NEG_SLOPE * e; w1 = adjc.y ? __expf(e) : 0.f;
            e = hsv + hdc.z; e = e >= 0.f ? e : NEG_SLOPE * e; w2 = adjc.z ? __expf(e) : 0.f;
            e = hsv + hdc.w; e = e >= 0.f ? e : NEG_SLOPE * e; w3 = adjc.w ? __expf(e) : 0.f;
            lsum += (w0 + w1) + (w2 + w3);
            bf16x4 wp; wp[0] = (bf16)w0; wp[1] = (bf16)w1; wp[2] = (bf16)w2; wp[3] = (bf16)w3;
            *(bf16x4*)((char*)&Wt[cur][0] + woff) = wp;
        }

        // drain this step's staging DMA (adj(s+1),hd(s+1),stage(s+1)=4 stay in flight)
        if (s + 1 < NS) asm volatile("s_waitcnt vmcnt(4)" ::: "memory");
        else            asm volatile("s_waitcnt vmcnt(0)" ::: "memory");
        asm volatile("s_waitcnt lgkmcnt(0)" ::: "memory");
        __builtin_amdgcn_s_barrier();

        // MFMA phase: 4 A-frags x 2 B-frags
        {
            const char* wb = (const char*)&Wt[cur][0];
            const char* bb = (const char*)&Bt[cur][0];
            bf16x8 a[4], b[2];
            #pragma unroll
            for (int sr = 0; sr < 4; ++sr)
                a[sr] = *(const bf16x8*)(wb + (sr * 16 + al) * 64 + eff);
            #pragma unroll
            for (int cf = 0; cf < 2; ++cf)
                b[cf] = *(const bf16x8*)(bb + (wv * 32 + cf * 16 + al) * 64 + eff);
            #pragma unroll
            for (int sr = 0; sr < 4; ++sr) {
                acc[sr][0] = __builtin_amdgcn_mfma_f32_16x16x32_bf16(a[sr], b[0], acc[sr][0], 0, 0, 0);
                acc[sr][1] = __builtin_amdgcn_mfma_f32_16x16x32_bf16(a[sr], b[1], acc[sr][1], 0, 0, 0);
            }
        }
        asm volatile("s_waitcnt lgkmcnt(0)" ::: "memory");
        __builtin_amdgcn_s_barrier();

        adjc = adjn; hdc = hdn;
    }

    // row sums: 8 threads per row (lanes t&7), then one atomic per row
    lsum += __shfl_xor(lsum, 1);
    lsum += __shfl_xor(lsum, 2);
    lsum += __shfl_xor(lsum, 4);
    if ((t & 7) == 0) atomicAdd(&lg[i0 + r], lsum);

    // numerator: JS atomic contributions per element
    #pragma unroll
    for (int sr = 0; sr < 4; ++sr) {
        #pragma unroll
        for (int cf = 0; cf < 2; ++cf) {
            #pragma unroll
            for (int g = 0; g < 4; ++g) {
                atomicAdd(&out[(size_t)(i0 + sr * 16 + asl * 4 + g) * FD + wv * 32 + cf * 16 + al],
                          acc[sr][cf][g]);
            }
        }
    }
}

// ---------------- K4: normalize by row sums ----------------
__global__ __launch_bounds__(256) void k_norm(float* __restrict__ out,
                                              const float* __restrict__ lg) {
    const int i = blockIdx.x;
    const float rinv = 1.0f / lg[i];
    out[(size_t)i * FD + threadIdx.x] *= rinv;
}

extern "C" void kernel_launch(void* const* d_in, const int* in_sizes, int n_in,
                              void* d_out, int out_size, void* d_ws, size_t ws_size,
                              hipStream_t stream) {
    const float* X     = (const float*)d_in[0];
    const int*   adj   = (const int*)d_in[1];
    const float* Ww    = (const float*)d_in[2];
    const float* Wb    = (const float*)d_in[3];
    const float* a_src = (const float*)d_in[4];
    const float* a_dst = (const float*)d_in[5];
    const float* a_b   = (const float*)d_in[6];
    float* out = (float*)d_out;

    bf16*  Ht = (bf16*)d_ws;                                  // 4.096 MB
    float* hs = (float*)((char*)d_ws + (size_t)FD * NN * sizeof(bf16));
    float* hd = hs + NN;
    float* lg = hd + NN;

    k_linear<<<NN / 16, 256, 0, stream>>>(X, Ww, Wb, Ht, out, lg);
    k_attn_vec<<<NN / 64, 256, 0, stream>>>(Ht, a_src, a_dst, a_b, hs, hd);
    k_gat<<<(NN / BM) * JS, 512, 0, stream>>>(Ht, adj, hs, hd, out, lg);
    k_norm<<<NN, 256, 0, stream>>>(out, lg);
}